// Round 17
// baseline (190.438 us; speedup 1.0000x reference)
//
#include <hip/hip_runtime.h>

typedef __attribute__((ext_vector_type(8))) short bh8;
typedef __attribute__((ext_vector_type(16))) float f16v;
typedef __attribute__((ext_vector_type(4))) unsigned int u32x4;

#define NTHR 512

__device__ __forceinline__ unsigned int f2bf(float f) {
    unsigned int u = __builtin_bit_cast(unsigned int, f);
    u += 0x7FFFu + ((u >> 16) & 1u);
    return u >> 16;
}
__device__ __forceinline__ float bflo(unsigned int d) {
    return __builtin_bit_cast(float, d << 16);
}
__device__ __forceinline__ float bfhi(unsigned int d) {
    return __builtin_bit_cast(float, d & 0xFFFF0000u);
}

// ---------------------------------------------------------------------------
// Kernel 1: x [B][C][H][W] f32 -> xt [B][H][W][C] bf16 (channel-last).
// ---------------------------------------------------------------------------
__global__ __launch_bounds__(256) void transpose_x_kernel(
    const float* __restrict__ x, unsigned short* __restrict__ xt) {
    __shared__ float tile[64 * 65];
    const int bid = blockIdx.x;            // 8*64*4 = 2048
    const int cq = bid & 3;
    const int h  = (bid >> 2) & 63;
    const int b  = bid >> 8;
    const int tid = threadIdx.x;
    const int w = tid & 63, ci = tid >> 6;
    #pragma unroll
    for (int c0 = 0; c0 < 64; c0 += 4)
        tile[(c0 + ci) * 65 + w] =
            x[(((size_t)b * 256 + cq * 64 + c0 + ci) * 64 + h) * 64 + w];
    __syncthreads();
    const int c2 = tid & 63, w2q = tid >> 6;
    #pragma unroll
    for (int w0 = 0; w0 < 64; w0 += 4) {
        int ww = w0 + w2q;
        xt[(((size_t)b * 64 + h) * 64 + ww) * 256 + cq * 64 + c2] =
            (unsigned short)f2bf(tile[c2 * 65 + ww]);
    }
}

// ---------------------------------------------------------------------------
// Kernel 2: pack w_d for 32x32x16 MFMA B-fragments; 16-ch chunks, tap-major.
// bp[((cc*9+tt)*8+nb)*64+l][e] = bf16(w_d[nb*32+(l&31)][(cc*16+(l>>5)*8+e)*9+tt])
// ---------------------------------------------------------------------------
__global__ __launch_bounds__(256) void pack_w16_kernel(const float* __restrict__ w_d,
                                                       bh8* __restrict__ bp) {
    __shared__ float ldw[32 * 145];
    const int cc = blockIdx.x >> 3;        // 0..15
    const int nb = blockIdx.x & 7;
    const int tid = threadIdx.x;
    for (int i = tid; i < 32 * 144; i += 256) {
        int oi = i / 144, j = i - oi * 144;
        ldw[oi * 145 + j] = w_d[(size_t)(nb * 32 + oi) * 2304 + cc * 144 + j];
    }
    __syncthreads();
    for (int u = tid; u < 9 * 64; u += 256) {
        int tt = u >> 6, ll = u & 63;
        int col = ll & 31, hi2 = ll >> 5;
        bh8 v;
        #pragma unroll
        for (int e = 0; e < 8; ++e)
            v[e] = (short)f2bf(ldw[col * 145 + (hi2 * 8 + e) * 9 + tt]);
        bp[((size_t)(cc * 9 + tt) * 8 + nb) * 64 + ll] = v;
    }
}

// ---------------------------------------------------------------------------
// Kernel 3: fused. Block = (b,h): 64 pixels x 256 outputs, 8 waves.
// 16-ch chunks (16 iters) -> LDS 32.4 KB -> 3 blocks/CU. Reg-staged halo
// tile (issue-early/write-late), scalar interpolation (f2 path miscompiles:
// R9/10/13 vs R14 controlled experiment), 32x32x16 MFMA, 2 M-halves/wave.
// ---------------------------------------------------------------------------
struct PK { float w00, w01, w10, w11; int A00, A01, sb; };

__global__ __launch_bounds__(NTHR, 6) void featadapt_mfma(
    const unsigned short* __restrict__ xt,
    const float* __restrict__ wh_pred,
    const float* __restrict__ w_off,
    const float* __restrict__ b_off,
    const float* __restrict__ b_d,
    const bh8* __restrict__ bp,
    float* __restrict__ out)
{
    extern __shared__ unsigned char lds[];
    unsigned char* samp = lds;                       // 64*288 = 18432
    unsigned char* tile = lds + 18432;               // 5*69*32 = 11040
    float* whs  = (float*)(lds + 29472);             // 512 f
    float* woff = (float*)(lds + 31520);             // 144 f
    float* boff = (float*)(lds + 32096);             // 72 f  (total 32384)

    const int tid  = threadIdx.x;
    const int orig = blockIdx.x;                     // 512 blocks
    const int bid  = (orig & 7) * 64 + (orig >> 3);  // XCD -> one batch image
    const int h = bid & 63;
    const int b = bid >> 6;

    {   // stage params
        int j = tid >> 6, p = tid & 63;
        whs[p * 8 + j] = wh_pred[(((size_t)b * 8 + j) * 64 + h) * 64 + p];
    }
    if (tid < 144) woff[tid] = w_off[tid];
    else if (tid < 216) boff[tid - 144] = b_off[tid - 144];

    const char* xtb = (const char*)xt + (size_t)b * (64 * 64 * 512);

    // ---- tile stage: 345 cells (5 rows x 69 cols) x 2 slots of 16B ----
    // LDS slot s holds global half (s&1) ^ H(cell), H = ((c>>2)+r)&1.
    auto slotsrc = [&](int s) -> int {
        int cell = s >> 1, j = s & 1;
        int r = cell / 69, c = cell - r * 69;
        int gy = min(max(h - 2 + r, 0), 63);
        int gx = min(max(c - 2, 0), 63);
        int od = j ^ (((c >> 2) + r) & 1);
        return (gy * 64 + gx) * 512 + od * 16;
    };
    const int sg0 = slotsrc(tid);
    const int sg1 = (tid < 178) ? slotsrc(512 + tid) : 0;
    unsigned char* const ld0 = tile + tid * 16;
    unsigned char* const ld1 = tile + 8192 + tid * 16;

    const int l  = tid & 63;
    const int wv = tid >> 6;
    const int arow = l & 31, hi = l >> 5;
    const int ab0 = arow * 288 + hi * 16;
    const int ab1 = ab0 + 32 * 288;
    const int asw = (arow & 7) << 4;

    // sampling ownership: main item (p, tap) = (wv*8 + l>>3, l&7);
    // extra: tap 8 -> lanes l<16: (p = wv*8 + l>>1, oct = l&1)
    const int pM = wv * 8 + (l >> 3), tM = l & 7;
    const int pE = wv * 8 + (l >> 1);

    auto calcpk = [&](int p, int tap, int g, PK& S) {
        float wh0 = whs[p * 8 + 2 * g], wh1 = whs[p * 8 + 2 * g + 1];
        int oy = 2 * tap, ox = oy + 1;
        float offy = wh0 * woff[(g * 18 + oy) * 2] + wh1 * woff[(g * 18 + oy) * 2 + 1] + boff[g * 18 + oy];
        float offx = wh0 * woff[(g * 18 + ox) * 2] + wh1 * woff[(g * 18 + ox) * 2 + 1] + boff[g * 18 + ox];
        int ky = tap / 3, kx = tap - ky * 3;
        float py = offy + (float)(ky - 1 + h);
        float px = offx + (float)(kx - 1 + p);
        float fy = floorf(py), fx = floorf(px);
        int y0 = (int)fy, x0 = (int)fx;
        float wy = py - fy, wx = px - fx;
        float my0 = (y0 >= 0 && y0 < 64) ? 1.f : 0.f;
        float my1 = (y0 >= -1 && y0 < 63) ? 1.f : 0.f;
        float mx0 = (x0 >= 0 && x0 < 64) ? 1.f : 0.f;
        float mx1 = (x0 >= -1 && x0 < 63) ? 1.f : 0.f;
        S.w00 = (1.f - wy) * (1.f - wx) * my0 * mx0;
        S.w01 = (1.f - wy) * wx * my0 * mx1;
        S.w10 = wy * (1.f - wx) * my1 * mx0;
        S.w11 = wy * wx * my1 * mx1;
        int r0 = y0 - (h - 2);                       // 0..3
        int c0 = x0 + 2, c1 = c0 + 1;                // 0..67
        S.A00 = (r0 * 69 + c0) * 32 + ((((c0 >> 2) + r0) & 1) << 4);
        S.A01 = (r0 * 69 + c1) * 32 + ((((c1 >> 2) + r0) & 1) << 4);
        S.sb  = (p * 288 + tap * 32) ^ ((p & 7) << 4);
    };

    auto sample_oct = [&](const PK& S, int oct) {
        int ox4 = oct << 4;
        u32x4 q00 = *(const u32x4*)(tile + (S.A00 ^ ox4));
        u32x4 q01 = *(const u32x4*)(tile + (S.A01 ^ ox4));
        u32x4 q10 = *(const u32x4*)(tile + (((S.A00 + 2208) ^ 16) ^ ox4));
        u32x4 q11 = *(const u32x4*)(tile + (((S.A01 + 2208) ^ 16) ^ ox4));
        unsigned int ow[4];
        #pragma unroll
        for (int j = 0; j < 4; ++j) {
            float sx = bflo(q00[j]) * S.w00 + bflo(q01[j]) * S.w01
                     + bflo(q10[j]) * S.w10 + bflo(q11[j]) * S.w11;
            float sy = bfhi(q00[j]) * S.w00 + bfhi(q01[j]) * S.w01
                     + bfhi(q10[j]) * S.w10 + bfhi(q11[j]) * S.w11;
            ow[j] = (__builtin_bit_cast(unsigned int, sx) >> 16)
                  | (__builtin_bit_cast(unsigned int, sy) & 0xFFFF0000u);
        }
        u32x4 o4 = {ow[0], ow[1], ow[2], ow[3]};
        *(u32x4*)(samp + (S.sb ^ ox4)) = o4;
    };

    f16v acc0, acc1;
    #pragma unroll
    for (int r = 0; r < 16; ++r) { acc0[r] = 0.f; acc1[r] = 0.f; }

    // ---- prologue: reg-stage tile chunk 0 ----
    {
        u32x4 t0 = *(const u32x4*)(xtb + sg0);
        u32x4 t1;
        if (tid < 178) t1 = *(const u32x4*)(xtb + sg1);
        *(u32x4*)ld0 = t0;
        if (tid < 178) *(u32x4*)ld1 = t1;
    }
    __syncthreads();   // params + tile(0) ready

    PK s0, s1;
    for (int cc = 0; cc < 16; ++cc) {
        if ((cc & 3) == 0) {
            int g = cc >> 2;
            calcpk(pM, tM, g, s0);
            if (l < 16) calcpk(pE, 8, g, s1);
        }
        // ---- issue next tile's loads EARLY (cover L2/HBM latency) ----
        u32x4 n0, n1;
        if (cc < 15) {
            const int off = (cc + 1) * 32;
            n0 = *(const u32x4*)(xtb + sg0 + off);
            if (tid < 178) n1 = *(const u32x4*)(xtb + sg1 + off);
        }

        // ---- sampling: read tile(cc), write samp ----
        sample_oct(s0, 0);
        sample_oct(s0, 1);
        if (l < 16) sample_oct(s1, l & 1);
        __syncthreads();   // (A) samp ready; tile consumed

        // ---- MFMA: 9 t-steps, 2 M-halves ----
        const bh8* bpc = bp + ((size_t)cc * 9 * 8 + wv) * 64 + l;
        __builtin_amdgcn_s_setprio(1);
        #pragma unroll
        for (int tt = 0; tt < 9; ++tt) {
            bh8 a0 = *(const bh8*)(samp + ((ab0 + tt * 32) ^ asw));
            bh8 a1 = *(const bh8*)(samp + ((ab1 + tt * 32) ^ asw));
            bh8 bw = bpc[(size_t)tt * 512];
            acc0 = __builtin_amdgcn_mfma_f32_32x32x16_bf16(a0, bw, acc0, 0, 0, 0);
            acc1 = __builtin_amdgcn_mfma_f32_32x32x16_bf16(a1, bw, acc1, 0, 0, 0);
        }
        __builtin_amdgcn_s_setprio(0);

        // ---- write next tile (write-late) ----
        if (cc < 15) {
            *(u32x4*)ld0 = n0;
            if (tid < 178) *(u32x4*)ld1 = n1;
        }
        __syncthreads();   // (B) tile(cc+1) ready; samp free
    }

    // ---- epilogue ----
    const int o = wv * 32 + arow;
    const float bd = b_d[o];
    const size_t ob = (((size_t)b * 256 + o) * 64 + h) * 64;
    #pragma unroll
    for (int q = 0; q < 4; ++q) {
        float4 s4a = make_float4(acc0[4 * q + 0] + bd, acc0[4 * q + 1] + bd,
                                 acc0[4 * q + 2] + bd, acc0[4 * q + 3] + bd);
        *(float4*)&out[ob + hi * 4 + q * 8] = s4a;
        float4 s4b = make_float4(acc1[4 * q + 0] + bd, acc1[4 * q + 1] + bd,
                                 acc1[4 * q + 2] + bd, acc1[4 * q + 3] + bd);
        *(float4*)&out[ob + 32 + hi * 4 + q * 8] = s4b;
    }
}

// ---------------------------------------------------------------------------
extern "C" void kernel_launch(void* const* d_in, const int* in_sizes, int n_in,
                              void* d_out, int out_size, void* d_ws, size_t ws_size,
                              hipStream_t stream) {
    const float* x     = (const float*)d_in[0];
    const float* whp   = (const float*)d_in[1];
    const float* w_off = (const float*)d_in[2];
    const float* b_off = (const float*)d_in[3];
    const float* w_d   = (const float*)d_in[4];
    const float* b_d   = (const float*)d_in[5];
    float* out = (float*)d_out;

    unsigned short* xt = (unsigned short*)d_ws;                    // 16.78 MB
    bh8* bp = (bh8*)((char*)d_ws + (size_t)8 * 64 * 64 * 256 * 2); // +1.18 MB

    hipLaunchKernelGGL(transpose_x_kernel, dim3(2048), dim3(256), 0, stream, x, xt);
    hipLaunchKernelGGL(pack_w16_kernel, dim3(128), dim3(256), 0, stream, w_d, bp);
    hipLaunchKernelGGL(featadapt_mfma, dim3(512), dim3(NTHR), 32384, stream,
                       xt, whp, w_off, b_off, b_d, bp, out);
}

// Round 18
// 86.689 us; speedup vs baseline: 2.1968x; 2.1968x over previous
//
#include <hip/hip_runtime.h>

typedef __attribute__((ext_vector_type(8))) short bh8;
typedef __attribute__((ext_vector_type(16))) float f16v;
typedef __attribute__((ext_vector_type(4))) unsigned int u32x4;

#define NTHR 512

__device__ __forceinline__ unsigned int f2bf(float f) {
    unsigned int u = __builtin_bit_cast(unsigned int, f);
    u += 0x7FFFu + ((u >> 16) & 1u);
    return u >> 16;
}
__device__ __forceinline__ float bflo(unsigned int d) {
    return __builtin_bit_cast(float, d << 16);
}
__device__ __forceinline__ float bfhi(unsigned int d) {
    return __builtin_bit_cast(float, d & 0xFFFF0000u);
}

// ---------------------------------------------------------------------------
// Kernel 1: x [B][C][H][W] f32 -> xt [B][H][W][C] bf16 (channel-last).
// ---------------------------------------------------------------------------
__global__ __launch_bounds__(256) void transpose_x_kernel(
    const float* __restrict__ x, unsigned short* __restrict__ xt) {
    __shared__ float tile[64 * 65];
    const int bid = blockIdx.x;            // 8*64*4 = 2048
    const int cq = bid & 3;
    const int h  = (bid >> 2) & 63;
    const int b  = bid >> 8;
    const int tid = threadIdx.x;
    const int w = tid & 63, ci = tid >> 6;
    #pragma unroll
    for (int c0 = 0; c0 < 64; c0 += 4)
        tile[(c0 + ci) * 65 + w] =
            x[(((size_t)b * 256 + cq * 64 + c0 + ci) * 64 + h) * 64 + w];
    __syncthreads();
    const int c2 = tid & 63, w2q = tid >> 6;
    #pragma unroll
    for (int w0 = 0; w0 < 64; w0 += 4) {
        int ww = w0 + w2q;
        xt[(((size_t)b * 64 + h) * 64 + ww) * 256 + cq * 64 + c2] =
            (unsigned short)f2bf(tile[c2 * 65 + ww]);
    }
}

// ---------------------------------------------------------------------------
// Kernel 2: pack w_d for 32x32x16 MFMA B-fragments; 16-ch chunks, tap-major.
// bp[((cc*9+tt)*8+nb)*64+l][e] = bf16(w_d[nb*32+(l&31)][(cc*16+(l>>5)*8+e)*9+tt])
// ---------------------------------------------------------------------------
__global__ __launch_bounds__(256) void pack_w16_kernel(const float* __restrict__ w_d,
                                                       bh8* __restrict__ bp) {
    __shared__ float ldw[32 * 145];
    const int cc = blockIdx.x >> 3;        // 0..15
    const int nb = blockIdx.x & 7;
    const int tid = threadIdx.x;
    for (int i = tid; i < 32 * 144; i += 256) {
        int oi = i / 144, j = i - oi * 144;
        ldw[oi * 145 + j] = w_d[(size_t)(nb * 32 + oi) * 2304 + cc * 144 + j];
    }
    __syncthreads();
    for (int u = tid; u < 9 * 64; u += 256) {
        int tt = u >> 6, ll = u & 63;
        int col = ll & 31, hi2 = ll >> 5;
        bh8 v;
        #pragma unroll
        for (int e = 0; e < 8; ++e)
            v[e] = (short)f2bf(ldw[col * 145 + (hi2 * 8 + e) * 9 + tt]);
        bp[((size_t)(cc * 9 + tt) * 8 + nb) * 64 + ll] = v;
    }
}

// ---------------------------------------------------------------------------
// Kernel 3: fused. Block = (b,h): 64 pixels x 256 outputs, 8 waves.
// 16-ch chunks (16 iters) -> LDS 32.4 KB -> 3-4 blocks/CU. Reg-staged halo
// tile (issue-early/write-late), scalar interpolation (f2 path miscompiles:
// R9/10/13 vs R14 controlled experiment), 32x32x16 MFMA, 2 M-halves/wave.
// R18 delta vs R17: __launch_bounds__(512,4) — R17's (512,6) caused a
// VGPR-40 spill catastrophe (219 MB FETCH); occupancy is LDS-governed.
// ---------------------------------------------------------------------------
struct PK { float w00, w01, w10, w11; int A00, A01, sb; };

__global__ __launch_bounds__(NTHR, 4) void featadapt_mfma(
    const unsigned short* __restrict__ xt,
    const float* __restrict__ wh_pred,
    const float* __restrict__ w_off,
    const float* __restrict__ b_off,
    const float* __restrict__ b_d,
    const bh8* __restrict__ bp,
    float* __restrict__ out)
{
    extern __shared__ unsigned char lds[];
    unsigned char* samp = lds;                       // 64*288 = 18432
    unsigned char* tile = lds + 18432;               // 5*69*32 = 11040
    float* whs  = (float*)(lds + 29472);             // 512 f
    float* woff = (float*)(lds + 31520);             // 144 f
    float* boff = (float*)(lds + 32096);             // 72 f  (total 32384)

    const int tid  = threadIdx.x;
    const int orig = blockIdx.x;                     // 512 blocks
    const int bid  = (orig & 7) * 64 + (orig >> 3);  // XCD -> one batch image
    const int h = bid & 63;
    const int b = bid >> 6;

    {   // stage params
        int j = tid >> 6, p = tid & 63;
        whs[p * 8 + j] = wh_pred[(((size_t)b * 8 + j) * 64 + h) * 64 + p];
    }
    if (tid < 144) woff[tid] = w_off[tid];
    else if (tid < 216) boff[tid - 144] = b_off[tid - 144];

    const char* xtb = (const char*)xt + (size_t)b * (64 * 64 * 512);

    // ---- tile stage: 345 cells (5 rows x 69 cols) x 2 slots of 16B ----
    // LDS slot s holds global half (s&1) ^ H(cell), H = ((c>>2)+r)&1.
    auto slotsrc = [&](int s) -> int {
        int cell = s >> 1, j = s & 1;
        int r = cell / 69, c = cell - r * 69;
        int gy = min(max(h - 2 + r, 0), 63);
        int gx = min(max(c - 2, 0), 63);
        int od = j ^ (((c >> 2) + r) & 1);
        return (gy * 64 + gx) * 512 + od * 16;
    };
    const int sg0 = slotsrc(tid);
    const int sg1 = (tid < 178) ? slotsrc(512 + tid) : 0;
    unsigned char* const ld0 = tile + tid * 16;
    unsigned char* const ld1 = tile + 8192 + tid * 16;

    const int l  = tid & 63;
    const int wv = tid >> 6;
    const int arow = l & 31, hi = l >> 5;
    const int ab0 = arow * 288 + hi * 16;
    const int ab1 = ab0 + 32 * 288;
    const int asw = (arow & 7) << 4;

    // sampling ownership: main item (p, tap) = (wv*8 + l>>3, l&7);
    // extra: tap 8 -> lanes l<16: (p = wv*8 + l>>1, oct = l&1)
    const int pM = wv * 8 + (l >> 3), tM = l & 7;
    const int pE = wv * 8 + (l >> 1);

    auto calcpk = [&](int p, int tap, int g, PK& S) {
        float wh0 = whs[p * 8 + 2 * g], wh1 = whs[p * 8 + 2 * g + 1];
        int oy = 2 * tap, ox = oy + 1;
        float offy = wh0 * woff[(g * 18 + oy) * 2] + wh1 * woff[(g * 18 + oy) * 2 + 1] + boff[g * 18 + oy];
        float offx = wh0 * woff[(g * 18 + ox) * 2] + wh1 * woff[(g * 18 + ox) * 2 + 1] + boff[g * 18 + ox];
        int ky = tap / 3, kx = tap - ky * 3;
        float py = offy + (float)(ky - 1 + h);
        float px = offx + (float)(kx - 1 + p);
        float fy = floorf(py), fx = floorf(px);
        int y0 = (int)fy, x0 = (int)fx;
        float wy = py - fy, wx = px - fx;
        float my0 = (y0 >= 0 && y0 < 64) ? 1.f : 0.f;
        float my1 = (y0 >= -1 && y0 < 63) ? 1.f : 0.f;
        float mx0 = (x0 >= 0 && x0 < 64) ? 1.f : 0.f;
        float mx1 = (x0 >= -1 && x0 < 63) ? 1.f : 0.f;
        S.w00 = (1.f - wy) * (1.f - wx) * my0 * mx0;
        S.w01 = (1.f - wy) * wx * my0 * mx1;
        S.w10 = wy * (1.f - wx) * my1 * mx0;
        S.w11 = wy * wx * my1 * mx1;
        int r0 = y0 - (h - 2);                       // 0..3
        int c0 = x0 + 2, c1 = c0 + 1;                // 0..67
        S.A00 = (r0 * 69 + c0) * 32 + ((((c0 >> 2) + r0) & 1) << 4);
        S.A01 = (r0 * 69 + c1) * 32 + ((((c1 >> 2) + r0) & 1) << 4);
        S.sb  = (p * 288 + tap * 32) ^ ((p & 7) << 4);
    };

    auto sample_oct = [&](const PK& S, int oct) {
        int ox4 = oct << 4;
        u32x4 q00 = *(const u32x4*)(tile + (S.A00 ^ ox4));
        u32x4 q01 = *(const u32x4*)(tile + (S.A01 ^ ox4));
        u32x4 q10 = *(const u32x4*)(tile + (((S.A00 + 2208) ^ 16) ^ ox4));
        u32x4 q11 = *(const u32x4*)(tile + (((S.A01 + 2208) ^ 16) ^ ox4));
        unsigned int ow[4];
        #pragma unroll
        for (int j = 0; j < 4; ++j) {
            float sx = bflo(q00[j]) * S.w00 + bflo(q01[j]) * S.w01
                     + bflo(q10[j]) * S.w10 + bflo(q11[j]) * S.w11;
            float sy = bfhi(q00[j]) * S.w00 + bfhi(q01[j]) * S.w01
                     + bfhi(q10[j]) * S.w10 + bfhi(q11[j]) * S.w11;
            ow[j] = (__builtin_bit_cast(unsigned int, sx) >> 16)
                  | (__builtin_bit_cast(unsigned int, sy) & 0xFFFF0000u);
        }
        u32x4 o4 = {ow[0], ow[1], ow[2], ow[3]};
        *(u32x4*)(samp + (S.sb ^ ox4)) = o4;
    };

    f16v acc0, acc1;
    #pragma unroll
    for (int r = 0; r < 16; ++r) { acc0[r] = 0.f; acc1[r] = 0.f; }

    // ---- prologue: reg-stage tile chunk 0 ----
    {
        u32x4 t0 = *(const u32x4*)(xtb + sg0);
        u32x4 t1;
        if (tid < 178) t1 = *(const u32x4*)(xtb + sg1);
        *(u32x4*)ld0 = t0;
        if (tid < 178) *(u32x4*)ld1 = t1;
    }
    __syncthreads();   // params + tile(0) ready

    PK s0, s1;
    for (int cc = 0; cc < 16; ++cc) {
        if ((cc & 3) == 0) {
            int g = cc >> 2;
            calcpk(pM, tM, g, s0);
            if (l < 16) calcpk(pE, 8, g, s1);
        }
        // ---- issue next tile's loads EARLY (cover L2/HBM latency) ----
        u32x4 n0, n1;
        if (cc < 15) {
            const int off = (cc + 1) * 32;
            n0 = *(const u32x4*)(xtb + sg0 + off);
            if (tid < 178) n1 = *(const u32x4*)(xtb + sg1 + off);
        }

        // ---- sampling: read tile(cc), write samp ----
        sample_oct(s0, 0);
        sample_oct(s0, 1);
        if (l < 16) sample_oct(s1, l & 1);
        __syncthreads();   // (A) samp ready; tile consumed

        // ---- MFMA: 9 t-steps, 2 M-halves ----
        const bh8* bpc = bp + ((size_t)cc * 9 * 8 + wv) * 64 + l;
        __builtin_amdgcn_s_setprio(1);
        #pragma unroll
        for (int tt = 0; tt < 9; ++tt) {
            bh8 a0 = *(const bh8*)(samp + ((ab0 + tt * 32) ^ asw));
            bh8 a1 = *(const bh8*)(samp + ((ab1 + tt * 32) ^ asw));
            bh8 bw = bpc[(size_t)tt * 512];
            acc0 = __builtin_amdgcn_mfma_f32_32x32x16_bf16(a0, bw, acc0, 0, 0, 0);
            acc1 = __builtin_amdgcn_mfma_f32_32x32x16_bf16(a1, bw, acc1, 0, 0, 0);
        }
        __builtin_amdgcn_s_setprio(0);

        // ---- write next tile (write-late) ----
        if (cc < 15) {
            *(u32x4*)ld0 = n0;
            if (tid < 178) *(u32x4*)ld1 = n1;
        }
        __syncthreads();   // (B) tile(cc+1) ready; samp free
    }

    // ---- epilogue ----
    const int o = wv * 32 + arow;
    const float bd = b_d[o];
    const size_t ob = (((size_t)b * 256 + o) * 64 + h) * 64;
    #pragma unroll
    for (int q = 0; q < 4; ++q) {
        float4 s4a = make_float4(acc0[4 * q + 0] + bd, acc0[4 * q + 1] + bd,
                                 acc0[4 * q + 2] + bd, acc0[4 * q + 3] + bd);
        *(float4*)&out[ob + hi * 4 + q * 8] = s4a;
        float4 s4b = make_float4(acc1[4 * q + 0] + bd, acc1[4 * q + 1] + bd,
                                 acc1[4 * q + 2] + bd, acc1[4 * q + 3] + bd);
        *(float4*)&out[ob + 32 + hi * 4 + q * 8] = s4b;
    }
}

// ---------------------------------------------------------------------------
extern "C" void kernel_launch(void* const* d_in, const int* in_sizes, int n_in,
                              void* d_out, int out_size, void* d_ws, size_t ws_size,
                              hipStream_t stream) {
    const float* x     = (const float*)d_in[0];
    const float* whp   = (const float*)d_in[1];
    const float* w_off = (const float*)d_in[2];
    const float* b_off = (const float*)d_in[3];
    const float* w_d   = (const float*)d_in[4];
    const float* b_d   = (const float*)d_in[5];
    float* out = (float*)d_out;

    unsigned short* xt = (unsigned short*)d_ws;                    // 16.78 MB
    bh8* bp = (bh8*)((char*)d_ws + (size_t)8 * 64 * 64 * 256 * 2); // +1.18 MB

    hipLaunchKernelGGL(transpose_x_kernel, dim3(2048), dim3(256), 0, stream, x, xt);
    hipLaunchKernelGGL(pack_w16_kernel, dim3(128), dim3(256), 0, stream, w_d, bp);
    hipLaunchKernelGGL(featadapt_mfma, dim3(512), dim3(NTHR), 32384, stream,
                       xt, whp, w_off, b_off, b_d, bp, out);
}

// Round 19
// 82.007 us; speedup vs baseline: 2.3222x; 1.0571x over previous
//
#include <hip/hip_runtime.h>
#include <hip/hip_fp16.h>

typedef __attribute__((ext_vector_type(8))) _Float16 h8;
typedef __attribute__((ext_vector_type(16))) float f16v;
typedef __attribute__((ext_vector_type(4))) unsigned int u32x4;

#define NTHR 512

__device__ __forceinline__ unsigned short f2h(float f) {
    _Float16 h = (_Float16)f;
    return __builtin_bit_cast(unsigned short, h);
}
__device__ __forceinline__ __half2 u2h2(unsigned int u) {
    union { unsigned int u; __half2 h; } cv; cv.u = u; return cv.h;
}
__device__ __forceinline__ unsigned int h22u(__half2 h) {
    union { unsigned int u; __half2 h; } cv; cv.h = h; return cv.u;
}

// ---------------------------------------------------------------------------
// Kernel 1: x [B][C][H][W] f32 -> xt [B][H][W][C] f16 (channel-last).
// ---------------------------------------------------------------------------
__global__ __launch_bounds__(256) void transpose_x_kernel(
    const float* __restrict__ x, unsigned short* __restrict__ xt) {
    __shared__ float tile[64 * 65];
    const int bid = blockIdx.x;            // 8*64*4 = 2048
    const int cq = bid & 3;
    const int h  = (bid >> 2) & 63;
    const int b  = bid >> 8;
    const int tid = threadIdx.x;
    const int w = tid & 63, ci = tid >> 6;
    #pragma unroll
    for (int c0 = 0; c0 < 64; c0 += 4)
        tile[(c0 + ci) * 65 + w] =
            x[(((size_t)b * 256 + cq * 64 + c0 + ci) * 64 + h) * 64 + w];
    __syncthreads();
    const int c2 = tid & 63, w2q = tid >> 6;
    #pragma unroll
    for (int w0 = 0; w0 < 64; w0 += 4) {
        int ww = w0 + w2q;
        xt[(((size_t)b * 64 + h) * 64 + ww) * 256 + cq * 64 + c2] =
            f2h(tile[c2 * 65 + ww]);
    }
}

// ---------------------------------------------------------------------------
// Kernel 2: pack w_d for 32x32x16 MFMA B-fragments (f16), tap-major K.
// ---------------------------------------------------------------------------
__global__ __launch_bounds__(256) void pack_w32_kernel(const float* __restrict__ w_d,
                                                       h8* __restrict__ bp) {
    __shared__ float ldw[32 * 289];
    const int cc = blockIdx.x >> 3;
    const int nb = blockIdx.x & 7;
    const int tid = threadIdx.x;
    for (int i = tid; i < 32 * 288; i += 256) {
        int oi = i / 288, j = i - oi * 288;
        ldw[oi * 289 + j] = w_d[((size_t)(nb * 32 + oi)) * 2304 + cc * 288 + j];
    }
    __syncthreads();
    for (int u = tid; u < 18 * 64; u += 256) {
        int tt2 = u >> 6, l = u & 63;
        int col = l & 31, hi = l >> 5;
        int tap = tt2 >> 1;
        int cb  = (tt2 & 1) * 16 + hi * 8;
        h8 v;
        #pragma unroll
        for (int e = 0; e < 8; ++e)
            v[e] = (_Float16)ldw[col * 289 + (cb + e) * 9 + tap];
        bp[((size_t)(cc * 18 + tt2) * 8 + nb) * 64 + l] = v;
    }
}

// ---------------------------------------------------------------------------
// Kernel 3: fused (R12 structure, proven). R19 delta: f16 data path —
// packed __hfma2 interpolation (4 ops per 2 channels, no extract/pack)
// + mfma_f32_32x32x16_f16. Address math identical to R12.
// ---------------------------------------------------------------------------
struct PK { __half2 W00, W01, W10, W11; int A00, A01, A10, A11, sb; };

__global__ __launch_bounds__(NTHR, 4) void featadapt_mfma(
    const unsigned short* __restrict__ xt,
    const float* __restrict__ wh_pred,
    const float* __restrict__ w_off,
    const float* __restrict__ b_off,
    const float* __restrict__ b_d,
    const h8* __restrict__ bp,
    float* __restrict__ out)
{
    extern __shared__ unsigned char lds[];
    unsigned char* samp = lds;                       // 64*576 = 36864
    unsigned char* tile = lds + 36864;               // 5*68*64 = 21760
    float* whs  = (float*)(lds + 58624);             // 512 f
    float* woff = (float*)(lds + 60672);             // 144 f
    float* boff = (float*)(lds + 61248);             // 72 f  (total 61536)

    const int tid  = threadIdx.x;
    const int orig = blockIdx.x;                     // 512 blocks
    const int bid  = (orig & 7) * 64 + (orig >> 3);  // XCD -> one batch image
    const int h = bid & 63;
    const int b = bid >> 6;

    {   // stage params
        int j = tid >> 6, p = tid & 63;
        whs[p * 8 + j] = wh_pred[(((size_t)b * 8 + j) * 64 + h) * 64 + p];
    }
    if (tid < 144) woff[tid] = w_off[tid];
    else if (tid < 216) boff[tid - 144] = b_off[tid - 144];

    const char* xtb = (const char*)xt + (size_t)b * (64 * 64 * 512);

    // ---- tile stage slots: 340 cells x 4 octs; row+col hashed source oct ----
    auto slotsrc = [&](int s) -> int {
        int cell = s >> 2, oct = s & 3;
        int row = cell / 68, col = cell - row * 68;
        int gy = min(max(h - 2 + row, 0), 63);
        int gx = min(max(col - 2, 0), 63);
        int osrc = oct ^ ((col + (col >> 2) + row) & 3);
        return (gy * 64 + gx) * 512 + osrc * 16;
    };
    const int sg0 = slotsrc(tid);
    const int sg1 = slotsrc(tid + 512);
    const int sg2 = slotsrc(tid + 1024);             // used only if tid<336
    unsigned char* const ld0 = tile + tid * 16;
    unsigned char* const ld1 = tile + 8192 + tid * 16;
    unsigned char* const ld2 = tile + 16384 + tid * 16;

    const int l  = tid & 63;
    const int wv = tid >> 6;
    const int arow = l & 31, hi = l >> 5;
    const int ab0 = arow * 576 + hi * 16;
    const int ab1 = ab0 + 32 * 576;
    const int asw = (arow & 7) << 4;

    // sampling: wave wv owns pks [wv*72, wv*72+72)
    const int pkA = wv * 72 + l;
    const int pkB = wv * 72 + 64 + (l >> 2);         // lanes l<32, oct = l&3

    auto calcpk = [&](int pk, int g, PK& S) {
        int p = pk / 9, k = pk - p * 9;
        float wh0 = whs[p * 8 + 2 * g], wh1 = whs[p * 8 + 2 * g + 1];
        int oy = 2 * k, ox = oy + 1;
        float offy = wh0 * woff[(g * 18 + oy) * 2] + wh1 * woff[(g * 18 + oy) * 2 + 1] + boff[g * 18 + oy];
        float offx = wh0 * woff[(g * 18 + ox) * 2] + wh1 * woff[(g * 18 + ox) * 2 + 1] + boff[g * 18 + ox];
        int ky = k / 3, kx = k - ky * 3;
        float py = offy + (float)(ky - 1 + h);
        float px = offx + (float)(kx - 1 + p);
        float fy = floorf(py), fx = floorf(px);
        int y0 = (int)fy, x0 = (int)fx;
        float wy = py - fy, wx = px - fx;
        float my0 = (y0 >= 0 && y0 < 64) ? 1.f : 0.f;
        float my1 = (y0 >= -1 && y0 < 63) ? 1.f : 0.f;
        float mx0 = (x0 >= 0 && x0 < 64) ? 1.f : 0.f;
        float mx1 = (x0 >= -1 && x0 < 63) ? 1.f : 0.f;
        S.W00 = __float2half2_rn((1.f - wy) * (1.f - wx) * my0 * mx0);
        S.W01 = __float2half2_rn((1.f - wy) * wx * my0 * mx1);
        S.W10 = __float2half2_rn(wy * (1.f - wx) * my1 * mx0);
        S.W11 = __float2half2_rn(wy * wx * my1 * mx1);
        int r0 = y0 - (h - 2), r1 = r0 + 1;          // 0..3 / 1..4
        int c0 = x0 + 2, c1 = c0 + 1;                // 0..67
        S.A00 = (r0 * 68 + c0) * 64 + (((c0 + (c0 >> 2) + r0) & 3) << 4);
        S.A01 = (r0 * 68 + c1) * 64 + (((c1 + (c1 >> 2) + r0) & 3) << 4);
        S.A10 = (r1 * 68 + c0) * 64 + (((c0 + (c0 >> 2) + r1) & 3) << 4);
        S.A11 = (r1 * 68 + c1) * 64 + (((c1 + (c1 >> 2) + r1) & 3) << 4);
        S.sb  = (p * 576 + k * 64) ^ ((p & 7) << 4) ^ (((k >> 1) & 3) << 4);
    };

    auto sample_oct = [&](const PK& S, int oct) {
        int ox4 = oct << 4;
        u32x4 q00 = *(const u32x4*)(tile + (S.A00 ^ ox4));
        u32x4 q01 = *(const u32x4*)(tile + (S.A01 ^ ox4));
        u32x4 q10 = *(const u32x4*)(tile + (S.A10 ^ ox4));
        u32x4 q11 = *(const u32x4*)(tile + (S.A11 ^ ox4));
        unsigned int ow[4];
        #pragma unroll
        for (int j = 0; j < 4; ++j) {
            __half2 s = __hfma2(u2h2(q00[j]), S.W00,
                        __hfma2(u2h2(q01[j]), S.W01,
                        __hfma2(u2h2(q10[j]), S.W10,
                        __hmul2(u2h2(q11[j]), S.W11))));
            ow[j] = h22u(s);
        }
        u32x4 o4 = {ow[0], ow[1], ow[2], ow[3]};
        *(u32x4*)(samp + (S.sb ^ ox4)) = o4;
    };

    f16v acc0, acc1;
    #pragma unroll
    for (int r = 0; r < 16; ++r) { acc0[r] = 0.f; acc1[r] = 0.f; }

    // ---- prologue: stage tile chunk 0 ----
    {
        u32x4 g0 = *(const u32x4*)(xtb + sg0);
        u32x4 g1 = *(const u32x4*)(xtb + sg1);
        *(u32x4*)ld0 = g0;
        *(u32x4*)ld1 = g1;
        if (tid < 336) {
            u32x4 g2 = *(const u32x4*)(xtb + sg2);
            *(u32x4*)ld2 = g2;
        }
    }
    __syncthreads();   // params + tile(0) ready

    PK s0, s1;
    for (int g = 0; g < 4; ++g) {
        calcpk(pkA, g, s0);
        if (l < 32) calcpk(pkB, g, s1);
        #pragma unroll
        for (int sub = 0; sub < 2; ++sub) {
            const int cc = g * 2 + sub;

            // ---- issue next tile's loads EARLY (cover L2/HBM latency) ----
            u32x4 g0v, g1v, g2v;
            const int nxt = (cc + 1) * 64;
            if (cc < 7) {
                g0v = *(const u32x4*)(xtb + sg0 + nxt);
                g1v = *(const u32x4*)(xtb + sg1 + nxt);
                if (tid < 336) g2v = *(const u32x4*)(xtb + sg2 + nxt);
            }

            // ---- sampling phase: read tile, write samp (balanced map) ----
            #pragma unroll
            for (int oct = 0; oct < 4; ++oct) sample_oct(s0, oct);
            if (l < 32) sample_oct(s1, l & 3);
            __syncthreads();   // samp ready; tile free

            // ---- MFMA: 18 t-steps, 2 M-halves ----
            const h8* bpc = bp + ((size_t)cc * 18 * 8 + wv) * 64 + l;
            __builtin_amdgcn_s_setprio(1);
            #pragma unroll 6
            for (int tt2 = 0; tt2 < 18; ++tt2) {
                const int kx4 = ((tt2 >> 2) & 3) << 4;
                h8 a0 = *(const h8*)(samp + (((ab0 + tt2 * 32) ^ asw) ^ kx4));
                h8 a1 = *(const h8*)(samp + (((ab1 + tt2 * 32) ^ asw) ^ kx4));
                h8 bw = bpc[(size_t)tt2 * 512];
                acc0 = __builtin_amdgcn_mfma_f32_32x32x16_f16(a0, bw, acc0, 0, 0, 0);
                acc1 = __builtin_amdgcn_mfma_f32_32x32x16_f16(a1, bw, acc1, 0, 0, 0);
            }
            __builtin_amdgcn_s_setprio(0);

            // ---- write next tile ----
            if (cc < 7) {
                *(u32x4*)ld0 = g0v;
                *(u32x4*)ld1 = g1v;
                if (tid < 336) *(u32x4*)ld2 = g2v;
            }
            __syncthreads();   // tile(cc+1) ready; MFMA done -> samp free
        }
    }

    // ---- epilogue ----
    const int o = wv * 32 + arow;
    const float bd = b_d[o];
    const size_t ob = (((size_t)b * 256 + o) * 64 + h) * 64;
    #pragma unroll
    for (int q = 0; q < 4; ++q) {
        float4 s4a = make_float4(acc0[4 * q + 0] + bd, acc0[4 * q + 1] + bd,
                                 acc0[4 * q + 2] + bd, acc0[4 * q + 3] + bd);
        *(float4*)&out[ob + hi * 4 + q * 8] = s4a;
        float4 s4b = make_float4(acc1[4 * q + 0] + bd, acc1[4 * q + 1] + bd,
                                 acc1[4 * q + 2] + bd, acc1[4 * q + 3] + bd);
        *(float4*)&out[ob + 32 + hi * 4 + q * 8] = s4b;
    }
}

// ---------------------------------------------------------------------------
extern "C" void kernel_launch(void* const* d_in, const int* in_sizes, int n_in,
                              void* d_out, int out_size, void* d_ws, size_t ws_size,
                              hipStream_t stream) {
    const float* x     = (const float*)d_in[0];
    const float* whp   = (const float*)d_in[1];
    const float* w_off = (const float*)d_in[2];
    const float* b_off = (const float*)d_in[3];
    const float* w_d   = (const float*)d_in[4];
    const float* b_d   = (const float*)d_in[5];
    float* out = (float*)d_out;

    unsigned short* xt = (unsigned short*)d_ws;                    // 16.78 MB
    h8* bp = (h8*)((char*)d_ws + (size_t)8 * 64 * 64 * 256 * 2);   // +1.18 MB

    hipLaunchKernelGGL(transpose_x_kernel, dim3(2048), dim3(256), 0, stream, x, xt);
    hipLaunchKernelGGL(pack_w32_kernel, dim3(64), dim3(256), 0, stream, w_d, bp);
    hipLaunchKernelGGL(featadapt_mfma, dim3(512), dim3(NTHR), 61536, stream,
                       xt, whp, w_off, b_off, b_d, bp, out);
}

// Round 20
// 79.791 us; speedup vs baseline: 2.3867x; 1.0278x over previous
//
#include <hip/hip_runtime.h>
#include <hip/hip_fp16.h>

typedef __attribute__((ext_vector_type(8))) _Float16 h8;
typedef __attribute__((ext_vector_type(16))) float f16v;
typedef __attribute__((ext_vector_type(4))) unsigned int u32x4;

#define NTHR 512

__device__ __forceinline__ unsigned short f2h(float f) {
    _Float16 h = (_Float16)f;
    return __builtin_bit_cast(unsigned short, h);
}
__device__ __forceinline__ __half2 u2h2(unsigned int u) {
    union { unsigned int u; __half2 h; } cv; cv.u = u; return cv.h;
}
__device__ __forceinline__ unsigned int h22u(__half2 h) {
    union { unsigned int u; __half2 h; } cv; cv.h = h; return cv.u;
}

// ---------------------------------------------------------------------------
// Kernel 1: x [B][C][H][W] f32 -> xt [B][H][W][C] f16 (channel-last).
// ---------------------------------------------------------------------------
__global__ __launch_bounds__(256) void transpose_x_kernel(
    const float* __restrict__ x, unsigned short* __restrict__ xt) {
    __shared__ float tile[64 * 65];
    const int bid = blockIdx.x;            // 8*64*4 = 2048
    const int cq = bid & 3;
    const int h  = (bid >> 2) & 63;
    const int b  = bid >> 8;
    const int tid = threadIdx.x;
    const int w = tid & 63, ci = tid >> 6;
    #pragma unroll
    for (int c0 = 0; c0 < 64; c0 += 4)
        tile[(c0 + ci) * 65 + w] =
            x[(((size_t)b * 256 + cq * 64 + c0 + ci) * 64 + h) * 64 + w];
    __syncthreads();
    const int c2 = tid & 63, w2q = tid >> 6;
    #pragma unroll
    for (int w0 = 0; w0 < 64; w0 += 4) {
        int ww = w0 + w2q;
        xt[(((size_t)b * 64 + h) * 64 + ww) * 256 + cq * 64 + c2] =
            f2h(tile[c2 * 65 + ww]);
    }
}

// ---------------------------------------------------------------------------
// Kernel 2: pack w_d for 32x32x16 MFMA B-fragments (f16); 16-ch chunks.
// bp[((cc*9+tt)*8+nb)*64+l][e] = f16(w_d[nb*32+(l&31)][(cc*16+(l>>5)*8+e)*9+tt])
// ---------------------------------------------------------------------------
__global__ __launch_bounds__(256) void pack_w16_kernel(const float* __restrict__ w_d,
                                                       h8* __restrict__ bp) {
    __shared__ float ldw[32 * 145];
    const int cc = blockIdx.x >> 3;        // 0..15
    const int nb = blockIdx.x & 7;
    const int tid = threadIdx.x;
    for (int i = tid; i < 32 * 144; i += 256) {
        int oi = i / 144, j = i - oi * 144;
        ldw[oi * 145 + j] = w_d[(size_t)(nb * 32 + oi) * 2304 + cc * 144 + j];
    }
    __syncthreads();
    for (int u = tid; u < 9 * 64; u += 256) {
        int tt = u >> 6, ll = u & 63;
        int col = ll & 31, hi2 = ll >> 5;
        h8 v;
        #pragma unroll
        for (int e = 0; e < 8; ++e)
            v[e] = (_Float16)ldw[col * 145 + (hi2 * 8 + e) * 9 + tt];
        bp[((size_t)(cc * 9 + tt) * 8 + nb) * 64 + ll] = v;
    }
}

// ---------------------------------------------------------------------------
// Kernel 3: fused. Block = (b,h): 64 px x 256 out, 8 waves, 16-ch chunks.
// R20: DOUBLE-BUFFERED samp+tile, ONE barrier/chunk — sampling(cc) and
// MFMA(cc-1) share the inter-barrier region so VALU and matrix pipes
// co-issue across waves. f16 __hfma2 interp (R19), R18 address math.
// ---------------------------------------------------------------------------
struct PK { __half2 W00, W01, W10, W11; int A00, A01, sb; };

__global__ __launch_bounds__(NTHR, 4) void featadapt_mfma(
    const unsigned short* __restrict__ xt,
    const float* __restrict__ wh_pred,
    const float* __restrict__ w_off,
    const float* __restrict__ b_off,
    const float* __restrict__ b_d,
    const h8* __restrict__ bp,
    float* __restrict__ out)
{
    extern __shared__ unsigned char lds[];
    unsigned char* samp0 = lds;                      // 18432
    unsigned char* samp1 = lds + 18432;              // 18432
    unsigned char* tile0 = lds + 36864;              // 11040
    unsigned char* tile1 = lds + 47904;              // 11040
    float* whs  = (float*)(lds + 58944);             // 512 f
    float* woff = (float*)(lds + 60992);             // 144 f
    float* boff = (float*)(lds + 61568);             // 72 f (total 61856)

    const int tid  = threadIdx.x;
    const int orig = blockIdx.x;                     // 512 blocks
    const int bid  = (orig & 7) * 64 + (orig >> 3);  // XCD -> one batch image
    const int h = bid & 63;
    const int b = bid >> 6;

    {   // stage params
        int j = tid >> 6, p = tid & 63;
        whs[p * 8 + j] = wh_pred[(((size_t)b * 8 + j) * 64 + h) * 64 + p];
    }
    if (tid < 144) woff[tid] = w_off[tid];
    else if (tid < 216) boff[tid - 144] = b_off[tid - 144];

    const char* xtb = (const char*)xt + (size_t)b * (64 * 64 * 512);

    // ---- tile stage: 345 cells (5 rows x 69 cols) x 2 slots of 16B ----
    auto slotsrc = [&](int s) -> int {
        int cell = s >> 1, j = s & 1;
        int r = cell / 69, c = cell - r * 69;
        int gy = min(max(h - 2 + r, 0), 63);
        int gx = min(max(c - 2, 0), 63);
        int od = j ^ (((c >> 2) + r) & 1);
        return (gy * 64 + gx) * 512 + od * 16;
    };
    const int sg0 = slotsrc(tid);
    const int sg1 = (tid < 178) ? slotsrc(512 + tid) : 0;
    const int d0 = tid * 16, d1 = 8192 + tid * 16;

    const int l  = tid & 63;
    const int wv = tid >> 6;
    const int arow = l & 31, hi = l >> 5;
    const int ab0 = arow * 288 + hi * 16;
    const int ab1 = ab0 + 32 * 288;
    const int asw = (arow & 7) << 4;

    // sampling ownership: main (p, tap) = (wv*8 + l>>3, l&7);
    // extra tap-8 -> lanes l<16: (p = wv*8 + l>>1, oct = l&1)
    const int pM = wv * 8 + (l >> 3), tM = l & 7;
    const int pE = wv * 8 + (l >> 1);

    auto calcpk = [&](int p, int tap, int g, PK& S) {
        float wh0 = whs[p * 8 + 2 * g], wh1 = whs[p * 8 + 2 * g + 1];
        int oy = 2 * tap, ox = oy + 1;
        float offy = wh0 * woff[(g * 18 + oy) * 2] + wh1 * woff[(g * 18 + oy) * 2 + 1] + boff[g * 18 + oy];
        float offx = wh0 * woff[(g * 18 + ox) * 2] + wh1 * woff[(g * 18 + ox) * 2 + 1] + boff[g * 18 + ox];
        int ky = tap / 3, kx = tap - ky * 3;
        float py = offy + (float)(ky - 1 + h);
        float px = offx + (float)(kx - 1 + p);
        float fy = floorf(py), fx = floorf(px);
        int y0 = (int)fy, x0 = (int)fx;
        float wy = py - fy, wx = px - fx;
        float my0 = (y0 >= 0 && y0 < 64) ? 1.f : 0.f;
        float my1 = (y0 >= -1 && y0 < 63) ? 1.f : 0.f;
        float mx0 = (x0 >= 0 && x0 < 64) ? 1.f : 0.f;
        float mx1 = (x0 >= -1 && x0 < 63) ? 1.f : 0.f;
        S.W00 = __float2half2_rn((1.f - wy) * (1.f - wx) * my0 * mx0);
        S.W01 = __float2half2_rn((1.f - wy) * wx * my0 * mx1);
        S.W10 = __float2half2_rn(wy * (1.f - wx) * my1 * mx0);
        S.W11 = __float2half2_rn(wy * wx * my1 * mx1);
        int r0 = y0 - (h - 2);                       // 0..3
        int c0 = x0 + 2, c1 = c0 + 1;                // 0..67
        S.A00 = (r0 * 69 + c0) * 32 + ((((c0 >> 2) + r0) & 1) << 4);
        S.A01 = (r0 * 69 + c1) * 32 + ((((c1 >> 2) + r0) & 1) << 4);
        S.sb  = (p * 288 + tap * 32) ^ ((p & 7) << 4);
    };

    auto sample_oct = [&](const PK& S, int oct,
                          const unsigned char* tb, unsigned char* sp) {
        int ox4 = oct << 4;
        u32x4 q00 = *(const u32x4*)(tb + (S.A00 ^ ox4));
        u32x4 q01 = *(const u32x4*)(tb + (S.A01 ^ ox4));
        u32x4 q10 = *(const u32x4*)(tb + (((S.A00 + 2208) ^ 16) ^ ox4));
        u32x4 q11 = *(const u32x4*)(tb + (((S.A01 + 2208) ^ 16) ^ ox4));
        unsigned int ow[4];
        #pragma unroll
        for (int j = 0; j < 4; ++j) {
            __half2 s = __hfma2(u2h2(q00[j]), S.W00,
                        __hfma2(u2h2(q01[j]), S.W01,
                        __hfma2(u2h2(q10[j]), S.W10,
                        __hmul2(u2h2(q11[j]), S.W11))));
            ow[j] = h22u(s);
        }
        u32x4 o4 = {ow[0], ow[1], ow[2], ow[3]};
        *(u32x4*)(sp + (S.sb ^ ox4)) = o4;
    };

    f16v acc0, acc1;
    #pragma unroll
    for (int r = 0; r < 16; ++r) { acc0[r] = 0.f; acc1[r] = 0.f; }

    // ---- prologue: reg-stage tile chunk 0 into tile0 ----
    {
        u32x4 t0 = *(const u32x4*)(xtb + sg0);
        u32x4 t1;
        if (tid < 178) t1 = *(const u32x4*)(xtb + sg1);
        *(u32x4*)(tile0 + d0) = t0;
        if (tid < 178) *(u32x4*)(tile0 + d1) = t1;
    }
    __syncthreads();   // params + tile(0) ready

    PK s0, s1;
    for (int cc = 0; cc < 16; ++cc) {
        if ((cc & 3) == 0) {
            int g = cc >> 2;
            calcpk(pM, tM, g, s0);
            if (l < 16) calcpk(pE, 8, g, s1);
        }
        // ---- issue next tile's loads EARLY ----
        u32x4 n0, n1;
        if (cc < 15) {
            const int off = (cc + 1) * 32;
            n0 = *(const u32x4*)(xtb + sg0 + off);
            if (tid < 178) n1 = *(const u32x4*)(xtb + sg1 + off);
        }

        // ---- sample(cc): tile[cc&1] -> samp[cc&1] ----
        const unsigned char* tb = (cc & 1) ? tile1 : tile0;
        unsigned char* sp = (cc & 1) ? samp1 : samp0;
        sample_oct(s0, 0, tb, sp);
        sample_oct(s0, 1, tb, sp);
        if (l < 16) sample_oct(s1, l & 1, tb, sp);

        // ---- MFMA(cc-1): samp[(cc-1)&1] — overlaps other waves' sampling ----
        if (cc > 0) {
            const unsigned char* spp = (cc & 1) ? samp0 : samp1;
            const h8* bpc = bp + ((size_t)(cc - 1) * 9 * 8 + wv) * 64 + l;
            __builtin_amdgcn_s_setprio(1);
            #pragma unroll
            for (int tt = 0; tt < 9; ++tt) {
                h8 a0 = *(const h8*)(spp + ((ab0 + tt * 32) ^ asw));
                h8 a1 = *(const h8*)(spp + ((ab1 + tt * 32) ^ asw));
                h8 bw = bpc[(size_t)tt * 512];
                acc0 = __builtin_amdgcn_mfma_f32_32x32x16_f16(a0, bw, acc0, 0, 0, 0);
                acc1 = __builtin_amdgcn_mfma_f32_32x32x16_f16(a1, bw, acc1, 0, 0, 0);
            }
            __builtin_amdgcn_s_setprio(0);
        }

        // ---- write next tile -> tile[(cc+1)&1] ----
        if (cc < 15) {
            unsigned char* tn = (cc & 1) ? tile0 : tile1;
            *(u32x4*)(tn + d0) = n0;
            if (tid < 178) *(u32x4*)(tn + d1) = n1;
        }
        __syncthreads();   // single barrier per chunk
    }

    // ---- epilogue: MFMA(15) from samp1 ----
    {
        const h8* bpc = bp + ((size_t)15 * 9 * 8 + wv) * 64 + l;
        __builtin_amdgcn_s_setprio(1);
        #pragma unroll
        for (int tt = 0; tt < 9; ++tt) {
            h8 a0 = *(const h8*)(samp1 + ((ab0 + tt * 32) ^ asw));
            h8 a1 = *(const h8*)(samp1 + ((ab1 + tt * 32) ^ asw));
            h8 bw = bpc[(size_t)tt * 512];
            acc0 = __builtin_amdgcn_mfma_f32_32x32x16_f16(a0, bw, acc0, 0, 0, 0);
            acc1 = __builtin_amdgcn_mfma_f32_32x32x16_f16(a1, bw, acc1, 0, 0, 0);
        }
        __builtin_amdgcn_s_setprio(0);
    }

    // ---- C write ----
    const int o = wv * 32 + arow;
    const float bd = b_d[o];
    const size_t ob = (((size_t)b * 256 + o) * 64 + h) * 64;
    #pragma unroll
    for (int q = 0; q < 4; ++q) {
        float4 s4a = make_float4(acc0[4 * q + 0] + bd, acc0[4 * q + 1] + bd,
                                 acc0[4 * q + 2] + bd, acc0[4 * q + 3] + bd);
        *(float4*)&out[ob + hi * 4 + q * 8] = s4a;
        float4 s4b = make_float4(acc1[4 * q + 0] + bd, acc1[4 * q + 1] + bd,
                                 acc1[4 * q + 2] + bd, acc1[4 * q + 3] + bd);
        *(float4*)&out[ob + 32 + hi * 4 + q * 8] = s4b;
    }
}

// ---------------------------------------------------------------------------
extern "C" void kernel_launch(void* const* d_in, const int* in_sizes, int n_in,
                              void* d_out, int out_size, void* d_ws, size_t ws_size,
                              hipStream_t stream) {
    const float* x     = (const float*)d_in[0];
    const float* whp   = (const float*)d_in[1];
    const float* w_off = (const float*)d_in[2];
    const float* b_off = (const float*)d_in[3];
    const float* w_d   = (const float*)d_in[4];
    const float* b_d   = (const float*)d_in[5];
    float* out = (float*)d_out;

    unsigned short* xt = (unsigned short*)d_ws;                    // 16.78 MB
    h8* bp = (h8*)((char*)d_ws + (size_t)8 * 64 * 64 * 256 * 2);   // +1.18 MB

    hipLaunchKernelGGL(transpose_x_kernel, dim3(2048), dim3(256), 0, stream, x, xt);
    hipLaunchKernelGGL(pack_w16_kernel, dim3(128), dim3(256), 0, stream, w_d, bp);
    hipLaunchKernelGGL(featadapt_mfma, dim3(512), dim3(NTHR), 61856, stream,
                       xt, whp, w_off, b_off, b_d, bp, out);
}